// Round 9
// baseline (67.580 us; speedup 1.0000x reference)
//
#include <hip/hip_runtime.h>

// h_t = f_t * h_{t-1} + (1 - f_t) * z_t over [T=1024, B, H], scan along T.
// One thread per channel, ping-pong register batches, non-temporal stores
// for h (keeps f+z resident in the 256 MiB Infinity Cache across replays).
//
// R9 change: 256-thread blocks (128 blocks) instead of 64-thread blocks
// (512 blocks). The 4 waves of a block co-reside on one CU and advance in
// near-lockstep, so each timestep row is fetched as a temporally-clustered
// 1 KiB contiguous burst instead of four scattered 256 B bursts -> better
// DRAM page locality for the 128 KiB-strided per-block streams.

constexpr int T_STEPS = 1024;
constexpr int BATCH   = 16;   // time steps per register batch

__global__ __launch_bounds__(256) void fm_scan(const float* __restrict__ f,
                                               const float* __restrict__ z,
                                               float* __restrict__ h,
                                               int BH) {
    const int ch = blockIdx.x * blockDim.x + threadIdx.x;
    if (ch >= BH) return;

    const float* fp = f + ch;
    const float* zp = z + ch;
    float*       hp = h + ch;
    const size_t stride = (size_t)BH;

    float fA[BATCH], zA[BATCH], fB[BATCH], zB[BATCH];

    // Prologue: load batch A (t = 0..BATCH-1)
#pragma unroll
    for (int i = 0; i < BATCH; ++i) {
        fA[i] = fp[(size_t)i * stride];
        zA[i] = zp[(size_t)i * stride];
    }
    __builtin_amdgcn_sched_barrier(0);

    float hv = 0.0f;

    for (int t0 = 0; t0 < T_STEPS; t0 += 2 * BATCH) {
        // ---- Phase 1: load batch B (t0+BATCH), compute batch A (t0) ----
        if (t0 + BATCH < T_STEPS) {
#pragma unroll
            for (int i = 0; i < BATCH; ++i) {
                fB[i] = fp[(size_t)(t0 + BATCH + i) * stride];
                zB[i] = zp[(size_t)(t0 + BATCH + i) * stride];
            }
        }
        __builtin_amdgcn_sched_barrier(0);
#pragma unroll
        for (int i = 0; i < BATCH; ++i) {
            // h = f*h + (1-f)*z  ==  f*(h - z) + z
            hv = fA[i] * (hv - zA[i]) + zA[i];
            __builtin_nontemporal_store(hv, &hp[(size_t)(t0 + i) * stride]);
        }
        __builtin_amdgcn_sched_barrier(0);

        // ---- Phase 2: load batch A (t0+2*BATCH), compute batch B ----
        if (t0 + 2 * BATCH < T_STEPS) {
#pragma unroll
            for (int i = 0; i < BATCH; ++i) {
                fA[i] = fp[(size_t)(t0 + 2 * BATCH + i) * stride];
                zA[i] = zp[(size_t)(t0 + 2 * BATCH + i) * stride];
            }
        }
        __builtin_amdgcn_sched_barrier(0);
        if (t0 + BATCH < T_STEPS) {
#pragma unroll
            for (int i = 0; i < BATCH; ++i) {
                hv = fB[i] * (hv - zB[i]) + zB[i];
                __builtin_nontemporal_store(hv, &hp[(size_t)(t0 + BATCH + i) * stride]);
            }
        }
        __builtin_amdgcn_sched_barrier(0);
    }
}

extern "C" void kernel_launch(void* const* d_in, const int* in_sizes, int n_in,
                              void* d_out, int out_size, void* d_ws, size_t ws_size,
                              hipStream_t stream) {
    const float* f = (const float*)d_in[0];
    const float* z = (const float*)d_in[1];
    float*       h = (float*)d_out;

    const int BH = in_sizes[0] / T_STEPS;   // 32*1024 = 32768 channels

    const int block = 256;
    const int grid  = (BH + block - 1) / block;  // 128 blocks x 4 waves
    fm_scan<<<grid, block, 0, stream>>>(f, z, h, BH);
}